// Round 1
// baseline (8944.568 us; speedup 1.0000x reference)
//
#include <hip/hip_runtime.h>
#include <math.h>

#define M_TRAIN 100000
#define NQ 2048
#define DIM 128
#define KNN 16
#define NCLS 10
#define TILE 50
#define MAXCAND 1600

__device__ __forceinline__ bool better(float d1, int i1, float d2, int i2) {
    return (d1 < d2) || (d1 == d2 && i1 < i2);
}

// Kernel 0: squared norms of train rows. One wave (64 lanes) per row.
__global__ void knn_t2_kernel(const float* __restrict__ train, float* __restrict__ t2) {
    int gw = (blockIdx.x * blockDim.x + threadIdx.x) >> 6;
    int lane = threadIdx.x & 63;
    if (gw >= M_TRAIN) return;
    const float* r = train + (size_t)gw * DIM;
    float a = r[lane];
    float b = r[lane + 64];
    float s = a * a + b * b;
    #pragma unroll
    for (int off = 32; off > 0; off >>= 1)
        s += __shfl_down(s, off, 64);
    if (lane == 0) t2[gw] = s;
}

// Kernel 1: thread-per-query scan over one chunk of train points.
// Query vector in registers; train tile staged in LDS, read broadcast.
// Per-thread sorted top-16 on d^2 (sqrt is monotone; done in merge kernel).
__global__ void knn_scan_kernel(const float* __restrict__ x,
                                const float* __restrict__ train,
                                const float* __restrict__ t2,
                                float* __restrict__ cand_d,
                                int* __restrict__ cand_i,
                                int chunk_pts, int nchunks) {
    __shared__ float sT[TILE * DIM];
    __shared__ float sT2[TILE];
    int q = blockIdx.y * blockDim.x + threadIdx.x;   // 8 * 256 == 2048 exactly

    float4 qv[DIM / 4];
    const float4* xq = (const float4*)(x + (size_t)q * DIM);
    #pragma unroll
    for (int i = 0; i < DIM / 4; ++i) qv[i] = xq[i];
    float x2 = 0.f;
    #pragma unroll
    for (int i = 0; i < DIM / 4; ++i)
        x2 += qv[i].x * qv[i].x + qv[i].y * qv[i].y + qv[i].z * qv[i].z + qv[i].w * qv[i].w;

    float bd[KNN];
    int   bi[KNN];
    #pragma unroll
    for (int j = 0; j < KNN; ++j) { bd[j] = 3.4e38f; bi[j] = 0x7fffffff; }

    int p0 = blockIdx.x * chunk_pts;
    for (int t0 = 0; t0 < chunk_pts; t0 += TILE) {
        __syncthreads();
        // Stage TILE rows (TILE*128 floats) coalesced.
        const float4* src = (const float4*)(train + (size_t)(p0 + t0) * DIM);
        float4* dst = (float4*)sT;
        for (int i = threadIdx.x; i < TILE * (DIM / 4); i += blockDim.x) dst[i] = src[i];
        if (threadIdx.x < TILE) sT2[threadIdx.x] = t2[p0 + t0 + threadIdx.x];
        __syncthreads();

        for (int p = 0; p < TILE; ++p) {
            const float4* tp = (const float4*)(sT + p * DIM);
            float a0 = 0.f, a1 = 0.f, a2 = 0.f, a3 = 0.f;
            #pragma unroll
            for (int i = 0; i < DIM / 4; ++i) {
                float4 tv = tp[i];               // broadcast read: all lanes same addr
                a0 = fmaf(qv[i].x, tv.x, a0);
                a1 = fmaf(qv[i].y, tv.y, a1);
                a2 = fmaf(qv[i].z, tv.z, a2);
                a3 = fmaf(qv[i].w, tv.w, a3);
            }
            float dot = (a0 + a1) + (a2 + a3);
            float d2 = x2 + sT2[p] - 2.f * dot;
            int gidx = p0 + t0 + p;
            if (better(d2, gidx, bd[KNN - 1], bi[KNN - 1])) {
                bd[KNN - 1] = d2; bi[KNN - 1] = gidx;
                // One bubble pass restores sorted order (only last elem was new).
                #pragma unroll
                for (int j = KNN - 1; j >= 1; --j) {
                    if (better(bd[j], bi[j], bd[j - 1], bi[j - 1])) {
                        float td = bd[j]; bd[j] = bd[j - 1]; bd[j - 1] = td;
                        int   ti = bi[j]; bi[j] = bi[j - 1]; bi[j - 1] = ti;
                    }
                }
            }
        }
    }

    int c = blockIdx.x;
    float* cd = cand_d + ((size_t)q * nchunks + c) * KNN;
    int*   ci = cand_i + ((size_t)q * nchunks + c) * KNN;
    #pragma unroll
    for (int j = 0; j < KNN; ++j) { cd[j] = bd[j]; ci[j] = bi[j]; }
}

// Kernel 2: one wave per query. Merge per-chunk candidates to global top-16
// (lexicographic (d2, idx) min == lax.top_k lower-index tie-break), then the
// inverse-distance weighted vote, normalize, argmax (first max).
__global__ void knn_merge_kernel(const float* __restrict__ cand_d,
                                 const int* __restrict__ cand_i,
                                 const int* __restrict__ labels,
                                 float* __restrict__ out,
                                 int nc) {
    __shared__ float sd[MAXCAND];
    __shared__ int   si[MAXCAND];
    __shared__ float spr[NCLS];
    int q = blockIdx.x;
    int lane = threadIdx.x;   // blockDim == 64
    const float* cd = cand_d + (size_t)q * nc;
    const int*   ci = cand_i + (size_t)q * nc;
    for (int i = lane; i < nc; i += 64) { sd[i] = cd[i]; si[i] = ci[i]; }
    __syncthreads();

    float kd[KNN];
    int   ki[KNN];
    #pragma unroll
    for (int sel = 0; sel < KNN; ++sel) {
        float md = 3.4e38f; int mi = 0x7fffffff; int ml = -1;
        for (int i = lane; i < nc; i += 64) {
            if (better(sd[i], si[i], md, mi)) { md = sd[i]; mi = si[i]; ml = i; }
        }
        #pragma unroll
        for (int off = 32; off > 0; off >>= 1) {
            float od = __shfl_down(md, off, 64);
            int   oi = __shfl_down(mi, off, 64);
            int   ol = __shfl_down(ml, off, 64);
            if (better(od, oi, md, mi)) { md = od; mi = oi; ml = ol; }
        }
        md = __shfl(md, 0, 64); mi = __shfl(mi, 0, 64); ml = __shfl(ml, 0, 64);
        kd[sel] = md; ki[sel] = mi;
        if (lane == 0 && ml >= 0) { sd[ml] = 3.4e38f; si[ml] = 0x7fffffff; }
        __syncthreads();
    }

    if (lane == 0) {
        bool anyzero = false;
        float dist[KNN];
        #pragma unroll
        for (int j = 0; j < KNN; ++j) {
            dist[j] = sqrtf(fmaxf(kd[j], 0.f));
            if (dist[j] == 0.f) anyzero = true;
        }
        #pragma unroll
        for (int c = 0; c < NCLS; ++c) spr[c] = 0.f;
        #pragma unroll
        for (int j = 0; j < KNN; ++j) {
            float w = anyzero ? (dist[j] == 0.f ? 1.f : 0.f) : 1.f / dist[j];
            int lab = labels[ki[j]];
            spr[lab] += w;
        }
        float s = 0.f;
        #pragma unroll
        for (int c = 0; c < NCLS; ++c) s += spr[c];
        if (s == 0.f) s = 1.f;
        float inv = 1.f / s;
        float best = -1.f; int bc = 0;
        #pragma unroll
        for (int c = 0; c < NCLS; ++c) {
            float pv = spr[c] * inv;
            out[NQ + (size_t)q * NCLS + c] = pv;
            if (pv > best) { best = pv; bc = c; }
        }
        out[q] = (float)bc;   // pred written as float
    }
}

extern "C" void kernel_launch(void* const* d_in, const int* in_sizes, int n_in,
                              void* d_out, int out_size, void* d_ws, size_t ws_size,
                              hipStream_t stream) {
    const float* x      = (const float*)d_in[0];
    const float* train  = (const float*)d_in[1];
    const int*   labels = (const int*)d_in[2];
    float* out = (float*)d_out;

    // Workspace layout: t2[100000] (padded to 100352) | cand_d | cand_i.
    // Chunk count chosen from ws_size (fixed per session -> graph-capture safe).
    float* t2 = (float*)d_ws;
    static const int opts[] = {100, 50, 25, 20, 10, 8, 5, 4, 2, 1};
    int nchunks = 1;
    for (int i = 0; i < 10; ++i) {
        size_t need = (size_t)100352 * 4 + (size_t)2 * NQ * opts[i] * KNN * 4;
        if (need <= ws_size) { nchunks = opts[i]; break; }
    }
    float* cand_d = t2 + 100352;
    int*   cand_i = (int*)(cand_d + (size_t)NQ * nchunks * KNN);
    int chunk_pts = M_TRAIN / nchunks;   // all opts divide 100000 into TILE multiples

    knn_t2_kernel<<<(M_TRAIN * 64 + 255) / 256, 256, 0, stream>>>(train, t2);

    dim3 g1(nchunks, NQ / 256);
    knn_scan_kernel<<<g1, 256, 0, stream>>>(x, train, t2, cand_d, cand_i,
                                            chunk_pts, nchunks);

    knn_merge_kernel<<<NQ, 64, 0, stream>>>(cand_d, cand_i, labels, out,
                                            nchunks * KNN);
}

// Round 2
// 1850.854 us; speedup vs baseline: 4.8327x; 4.8327x over previous
//
#include <hip/hip_runtime.h>
#include <math.h>

#define M_TRAIN 100000
#define NQ 2048
#define DIM 128
#define KNN 16
#define NCLS 10

// Subsample (threshold) pass: every 16th train point.
#define S_STRIDE 16
#define S_CNT (M_TRAIN / S_STRIDE)     // 6250
#define S_CHUNKS 50
#define S_PER (S_CNT / S_CHUNKS)       // 125
#define STILE 25                       // LDS tile rows in subsample scan

// Filter pass
#define CAP 768                        // candidate buffer per query (mean ~256)
#define QSPLIT 4                       // query-dim grid split in filter
#define TAU_MARGIN 0.02f               // covers summation-order rounding diffs

__device__ __forceinline__ bool better(float d1, int i1, float d2, int i2) {
    return (d1 < d2) || (d1 == d2 && i1 < i2);
}

// ---------------------------------------------------------------------------
// Kernel 0: squared norms. One wave per row; rows [0,M) = train, [M,M+NQ) = x.
__global__ void knn_norms(const float* __restrict__ train,
                          const float* __restrict__ x,
                          float* __restrict__ t2, float* __restrict__ x2) {
    int gw = (blockIdx.x * blockDim.x + threadIdx.x) >> 6;
    int lane = threadIdx.x & 63;
    if (gw >= M_TRAIN + NQ) return;
    const float* r = (gw < M_TRAIN) ? (train + (size_t)gw * DIM)
                                    : (x + (size_t)(gw - M_TRAIN) * DIM);
    float a = r[lane];
    float b = r[lane + 64];
    float s = a * a + b * b;
    #pragma unroll
    for (int off = 32; off > 0; off >>= 1)
        s += __shfl_down(s, off, 64);
    if (lane == 0) {
        if (gw < M_TRAIN) t2[gw] = s; else x2[gw - M_TRAIN] = s;
    }
}

// Kernel 0b: zero the push counters (ws is poisoned 0xAA before every launch).
__global__ void knn_zero_cnt(int* __restrict__ cnt) {
    int i = blockIdx.x * blockDim.x + threadIdx.x;
    if (i < NQ) cnt[i] = 0;
}

// ---------------------------------------------------------------------------
// Kernel 1: exact top-16 over the stride-16 subsample, thread-per-query,
// chunked for parallelism. Query vector held in registers (spill-proof via
// __launch_bounds__(256,1) -> 512-VGPR cap).
__global__ __launch_bounds__(256, 1)
void knn_sub_scan(const float* __restrict__ x, const float* __restrict__ train,
                  const float* __restrict__ t2,
                  float* __restrict__ cand_d, int* __restrict__ cand_i) {
    __shared__ float sT[STILE * DIM];
    __shared__ float sT2[STILE];
    int q = blockIdx.y * blockDim.x + threadIdx.x;   // 8 * 256 == 2048
    int c = blockIdx.x;                              // subsample chunk

    float4 qv[DIM / 4];
    const float4* xq = (const float4*)(x + (size_t)q * DIM);
    #pragma unroll
    for (int i = 0; i < DIM / 4; ++i) qv[i] = xq[i];
    float x2l = 0.f;
    #pragma unroll
    for (int i = 0; i < DIM / 4; ++i)
        x2l += qv[i].x * qv[i].x + qv[i].y * qv[i].y + qv[i].z * qv[i].z + qv[i].w * qv[i].w;

    float bd[KNN];
    int   bi[KNN];
    #pragma unroll
    for (int j = 0; j < KNN; ++j) { bd[j] = 3.4e38f; bi[j] = 0x7fffffff; }

    for (int t0 = 0; t0 < S_PER; t0 += STILE) {
        __syncthreads();
        for (int i = threadIdx.x; i < STILE * (DIM / 4); i += blockDim.x) {
            int r = i >> 5, col = i & 31;
            size_t row = (size_t)(c * S_PER + t0 + r) * S_STRIDE;
            ((float4*)sT)[i] = ((const float4*)train)[row * (DIM / 4) + col];
        }
        if (threadIdx.x < STILE)
            sT2[threadIdx.x] = t2[(size_t)(c * S_PER + t0 + threadIdx.x) * S_STRIDE];
        __syncthreads();

        for (int p = 0; p < STILE; ++p) {
            const float4* tp = (const float4*)(sT + p * DIM);
            float a0 = 0.f, a1 = 0.f, a2 = 0.f, a3 = 0.f;
            #pragma unroll
            for (int i = 0; i < DIM / 4; ++i) {
                float4 tv = tp[i];
                a0 = fmaf(qv[i].x, tv.x, a0);
                a1 = fmaf(qv[i].y, tv.y, a1);
                a2 = fmaf(qv[i].z, tv.z, a2);
                a3 = fmaf(qv[i].w, tv.w, a3);
            }
            float dot = (a0 + a1) + (a2 + a3);
            float d2 = x2l + sT2[p] - 2.f * dot;
            int gidx = (c * S_PER + t0 + p) * S_STRIDE;
            if (better(d2, gidx, bd[KNN - 1], bi[KNN - 1])) {
                bd[KNN - 1] = d2; bi[KNN - 1] = gidx;
                #pragma unroll
                for (int j = KNN - 1; j >= 1; --j) {
                    if (better(bd[j], bi[j], bd[j - 1], bi[j - 1])) {
                        float td = bd[j]; bd[j] = bd[j - 1]; bd[j - 1] = td;
                        int   ti = bi[j]; bi[j] = bi[j - 1]; bi[j - 1] = ti;
                    }
                }
            }
        }
    }

    float* cd = cand_d + ((size_t)q * S_CHUNKS + c) * KNN;
    int*   ci = cand_i + ((size_t)q * S_CHUNKS + c) * KNN;
    #pragma unroll
    for (int j = 0; j < KNN; ++j) { cd[j] = bd[j]; ci[j] = bi[j]; }
}

// ---------------------------------------------------------------------------
// Kernel 2: merge per-chunk subsample candidates, emit tau[q] = 16th-best d2.
__global__ void knn_tau(const float* __restrict__ cand_d,
                        const int* __restrict__ cand_i,
                        float* __restrict__ tau) {
    __shared__ float sd[S_CHUNKS * KNN];
    __shared__ int   si[S_CHUNKS * KNN];
    int q = blockIdx.x;
    int lane = threadIdx.x;   // blockDim == 64
    const int nc = S_CHUNKS * KNN;
    const float* cd = cand_d + (size_t)q * nc;
    const int*   ci = cand_i + (size_t)q * nc;
    for (int i = lane; i < nc; i += 64) { sd[i] = cd[i]; si[i] = ci[i]; }
    __syncthreads();
    float last = 3.4e38f;
    #pragma unroll
    for (int sel = 0; sel < KNN; ++sel) {
        float md = 3.4e38f; int mi = 0x7fffffff; int ml = -1;
        for (int i = lane; i < nc; i += 64)
            if (better(sd[i], si[i], md, mi)) { md = sd[i]; mi = si[i]; ml = i; }
        #pragma unroll
        for (int off = 32; off > 0; off >>= 1) {
            float od = __shfl_down(md, off, 64);
            int   oi = __shfl_down(mi, off, 64);
            int   ol = __shfl_down(ml, off, 64);
            if (better(od, oi, md, mi)) { md = od; mi = oi; ml = ol; }
        }
        md = __shfl(md, 0, 64); ml = __shfl(ml, 0, 64);
        last = md;
        if (lane == 0 && ml >= 0) { sd[ml] = 3.4e38f; si[ml] = 0x7fffffff; }
        __syncthreads();
    }
    if (lane == 0) tau[q] = last;
}

// ---------------------------------------------------------------------------
// Kernel 3: the big pass. Each thread holds ONE train point in 128 VGPRs and
// streams all queries of its slice as wave-uniform (scalar) loads; inner loop
// is pure v_fma. Survivors of d2 <= tau are pushed (rare) to per-query bufs.
__global__ __launch_bounds__(256, 1)
void knn_filter(const float* __restrict__ x, const float* __restrict__ train,
                const float* __restrict__ x2, const float* __restrict__ tau,
                float* __restrict__ buf_d, int* __restrict__ buf_i,
                int* __restrict__ cnt) {
    int pidx = blockIdx.x * 256 + threadIdx.x;
    bool valid = pidx < M_TRAIN;
    const float4* tsrc = (const float4*)(train + (size_t)(valid ? pidx : 0) * DIM);
    float4 tp[DIM / 4];
    #pragma unroll
    for (int i = 0; i < DIM / 4; ++i) tp[i] = tsrc[i];
    float b0 = 0.f, b1 = 0.f, b2 = 0.f, b3 = 0.f;
    #pragma unroll
    for (int i = 0; i < DIM / 4; ++i) {
        b0 = fmaf(tp[i].x, tp[i].x, b0);
        b1 = fmaf(tp[i].y, tp[i].y, b1);
        b2 = fmaf(tp[i].z, tp[i].z, b2);
        b3 = fmaf(tp[i].w, tp[i].w, b3);
    }
    float t2p = (b0 + b1) + (b2 + b3);

    int q0 = blockIdx.y * (NQ / QSPLIT);
    int q1 = q0 + (NQ / QSPLIT);
    for (int q = q0; q < q1; ++q) {
        const float4* qp = (const float4*)(x + (size_t)q * DIM);  // uniform -> s_load
        float xq2 = x2[q];                                        // uniform
        float tq  = tau[q] + TAU_MARGIN;                          // uniform
        float a0 = 0.f, a1 = 0.f, a2 = 0.f, a3 = 0.f;
        #pragma unroll
        for (int i = 0; i < DIM / 4; ++i) {
            float4 qv = qp[i];
            a0 = fmaf(qv.x, tp[i].x, a0);
            a1 = fmaf(qv.y, tp[i].y, a1);
            a2 = fmaf(qv.z, tp[i].z, a2);
            a3 = fmaf(qv.w, tp[i].w, a3);
        }
        float dot = (a0 + a1) + (a2 + a3);
        float d2 = xq2 + t2p - 2.f * dot;
        if (valid && d2 <= tq) {
            int slot = atomicAdd(&cnt[q], 1);
            if (slot < CAP) {
                buf_d[(size_t)q * CAP + slot] = d2;
                buf_i[(size_t)q * CAP + slot] = pidx;
            }
        }
    }
}

// ---------------------------------------------------------------------------
// Kernel 4: exact re-rank of the pushed candidates + weighted vote + outputs.
__global__ void knn_final(const float* __restrict__ buf_d,
                          const int* __restrict__ buf_i,
                          const int* __restrict__ cnt,
                          const int* __restrict__ labels,
                          float* __restrict__ out) {
    __shared__ float sd[CAP];
    __shared__ int   si[CAP];
    __shared__ float spr[NCLS];
    int q = blockIdx.x;
    int lane = threadIdx.x;   // blockDim == 64
    int n = cnt[q]; if (n > CAP) n = CAP;
    for (int i = lane; i < n; i += 64) {
        sd[i] = buf_d[(size_t)q * CAP + i];
        si[i] = buf_i[(size_t)q * CAP + i];
    }
    __syncthreads();

    float kd[KNN];
    int   ki[KNN];
    #pragma unroll
    for (int sel = 0; sel < KNN; ++sel) {
        float md = 3.4e38f; int mi = 0x7fffffff; int ml = -1;
        for (int i = lane; i < n; i += 64)
            if (better(sd[i], si[i], md, mi)) { md = sd[i]; mi = si[i]; ml = i; }
        #pragma unroll
        for (int off = 32; off > 0; off >>= 1) {
            float od = __shfl_down(md, off, 64);
            int   oi = __shfl_down(mi, off, 64);
            int   ol = __shfl_down(ml, off, 64);
            if (better(od, oi, md, mi)) { md = od; mi = oi; ml = ol; }
        }
        md = __shfl(md, 0, 64); mi = __shfl(mi, 0, 64); ml = __shfl(ml, 0, 64);
        kd[sel] = md; ki[sel] = mi;
        if (lane == 0 && ml >= 0) { sd[ml] = 3.4e38f; si[ml] = 0x7fffffff; }
        __syncthreads();
    }

    if (lane == 0) {
        bool anyzero = false;
        float dist[KNN];
        #pragma unroll
        for (int j = 0; j < KNN; ++j) {
            dist[j] = sqrtf(fmaxf(kd[j], 0.f));
            if (dist[j] == 0.f) anyzero = true;
        }
        #pragma unroll
        for (int c = 0; c < NCLS; ++c) spr[c] = 0.f;
        #pragma unroll
        for (int j = 0; j < KNN; ++j) {
            float w = anyzero ? (dist[j] == 0.f ? 1.f : 0.f) : 1.f / dist[j];
            spr[labels[ki[j]]] += w;
        }
        float s = 0.f;
        #pragma unroll
        for (int c = 0; c < NCLS; ++c) s += spr[c];
        if (s == 0.f) s = 1.f;
        float inv = 1.f / s;
        float best = -1.f; int bc = 0;
        #pragma unroll
        for (int c = 0; c < NCLS; ++c) {
            float pv = spr[c] * inv;
            out[NQ + (size_t)q * NCLS + c] = pv;
            if (pv > best) { best = pv; bc = c; }
        }
        out[q] = (float)bc;
    }
}

// ---------------------------------------------------------------------------
extern "C" void kernel_launch(void* const* d_in, const int* in_sizes, int n_in,
                              void* d_out, int out_size, void* d_ws, size_t ws_size,
                              hipStream_t stream) {
    const float* x      = (const float*)d_in[0];
    const float* train  = (const float*)d_in[1];
    const int*   labels = (const int*)d_in[2];
    float* out = (float*)d_out;

    // Workspace layout (floats). Round-1 WRITE_SIZE evidence => ws_size >= 26.6 MB;
    // this layout needs 24.9 MiB.
    float* t2  = (float*)d_ws;                     // 100352 (padded)
    float* x2  = t2 + 100352;                      // 2048
    float* tau = x2 + NQ;                          // 2048
    int*   cnt = (int*)(tau + NQ);                 // 2048
    float* scd = (float*)(cnt + NQ);               // 2048*50*16
    int*   sci = (int*)(scd + (size_t)NQ * S_CHUNKS * KNN);
    float* bd  = (float*)(sci + (size_t)NQ * S_CHUNKS * KNN);  // 2048*768
    int*   bi  = (int*)(bd + (size_t)NQ * CAP);

    int nrows = M_TRAIN + NQ;
    knn_norms<<<(nrows * 64 + 255) / 256, 256, 0, stream>>>(train, x, t2, x2);
    knn_zero_cnt<<<(NQ + 255) / 256, 256, 0, stream>>>(cnt);

    dim3 g1(S_CHUNKS, NQ / 256);
    knn_sub_scan<<<g1, 256, 0, stream>>>(x, train, t2, scd, sci);

    knn_tau<<<NQ, 64, 0, stream>>>(scd, sci, tau);

    dim3 g3((M_TRAIN + 255) / 256, QSPLIT);
    knn_filter<<<g3, 256, 0, stream>>>(x, train, x2, tau, bd, bi, cnt);

    knn_final<<<NQ, 64, 0, stream>>>(bd, bi, cnt, labels, out);
}

// Round 3
// 1108.850 us; speedup vs baseline: 8.0665x; 1.6692x over previous
//
#include <hip/hip_runtime.h>
#include <math.h>

#define M_TRAIN 100000
#define NQ 2048
#define DIM 128
#define KNN 16
#define NCLS 10

// Subsample (threshold) pass: every 16th train point.
#define S_STRIDE 16
#define S_CNT (M_TRAIN / S_STRIDE)     // 6250
#define S_CHUNKS 50
#define S_PER (S_CNT / S_CHUNKS)       // 125
#define STILE 25

// MFMA filter pass
#define CAP 768
#define CHUNKS 32
#define TC (M_TRAIN / CHUNKS)          // 3125 train pts per block
#define TT 64                          // train tile rows per K-sweep
#define NT ((TC + TT - 1) / TT)        // 49 tiles (last partial: 53 rows)
#define MQ 128                         // queries per block
#define QSTR 136                       // LDS row stride in shorts (128 + 8 pad)
#define MARGIN 2.0f                    // >> 8 sigma of bf16 d2 error (~0.14)

using bfrag = __attribute__((ext_vector_type(8))) short;   // 8 bf16
using cfrag = __attribute__((ext_vector_type(4))) float;   // 4 f32 acc

__device__ __forceinline__ bool better(float d1, int i1, float d2, int i2) {
    return (d1 < d2) || (d1 == d2 && i1 < i2);
}

__device__ __forceinline__ unsigned pack_bf16(float a, float b) {
    unsigned ua = __float_as_uint(a), ub = __float_as_uint(b);
    ua += 0x7fffu + ((ua >> 16) & 1u);   // RNE
    ub += 0x7fffu + ((ub >> 16) & 1u);
    return (ua >> 16) | (ub & 0xffff0000u);
}

// ---------------------------------------------------------------------------
// Kernel 0: squared norms. One wave per row; rows [0,M) = train, [M,M+NQ) = x.
__global__ void knn_norms(const float* __restrict__ train,
                          const float* __restrict__ x,
                          float* __restrict__ t2, float* __restrict__ x2) {
    int gw = (blockIdx.x * blockDim.x + threadIdx.x) >> 6;
    int lane = threadIdx.x & 63;
    if (gw >= M_TRAIN + NQ) return;
    const float* r = (gw < M_TRAIN) ? (train + (size_t)gw * DIM)
                                    : (x + (size_t)(gw - M_TRAIN) * DIM);
    float a = r[lane];
    float b = r[lane + 64];
    float s = a * a + b * b;
    #pragma unroll
    for (int off = 32; off > 0; off >>= 1)
        s += __shfl_down(s, off, 64);
    if (lane == 0) {
        if (gw < M_TRAIN) t2[gw] = s; else x2[gw - M_TRAIN] = s;
    }
}

__global__ void knn_zero_cnt(int* __restrict__ cnt) {
    int i = blockIdx.x * blockDim.x + threadIdx.x;
    if (i < NQ) cnt[i] = 0;
}

// ---------------------------------------------------------------------------
// Kernel 1: exact fp32 top-16 over the stride-16 subsample (tau source).
__global__ __launch_bounds__(256, 1)
void knn_sub_scan(const float* __restrict__ x, const float* __restrict__ train,
                  const float* __restrict__ t2,
                  float* __restrict__ cand_d, int* __restrict__ cand_i) {
    __shared__ float sT[STILE * DIM];
    __shared__ float sT2[STILE];
    int q = blockIdx.y * blockDim.x + threadIdx.x;
    int c = blockIdx.x;

    float4 qv[DIM / 4];
    const float4* xq = (const float4*)(x + (size_t)q * DIM);
    #pragma unroll
    for (int i = 0; i < DIM / 4; ++i) qv[i] = xq[i];
    float x2l = 0.f;
    #pragma unroll
    for (int i = 0; i < DIM / 4; ++i)
        x2l += qv[i].x * qv[i].x + qv[i].y * qv[i].y + qv[i].z * qv[i].z + qv[i].w * qv[i].w;

    float bd[KNN];
    int   bi[KNN];
    #pragma unroll
    for (int j = 0; j < KNN; ++j) { bd[j] = 3.4e38f; bi[j] = 0x7fffffff; }

    for (int t0 = 0; t0 < S_PER; t0 += STILE) {
        __syncthreads();
        for (int i = threadIdx.x; i < STILE * (DIM / 4); i += blockDim.x) {
            int r = i >> 5, col = i & 31;
            size_t row = (size_t)(c * S_PER + t0 + r) * S_STRIDE;
            ((float4*)sT)[i] = ((const float4*)train)[row * (DIM / 4) + col];
        }
        if (threadIdx.x < STILE)
            sT2[threadIdx.x] = t2[(size_t)(c * S_PER + t0 + threadIdx.x) * S_STRIDE];
        __syncthreads();

        for (int p = 0; p < STILE; ++p) {
            const float4* tp = (const float4*)(sT + p * DIM);
            float a0 = 0.f, a1 = 0.f, a2 = 0.f, a3 = 0.f;
            #pragma unroll
            for (int i = 0; i < DIM / 4; ++i) {
                float4 tv = tp[i];
                a0 = fmaf(qv[i].x, tv.x, a0);
                a1 = fmaf(qv[i].y, tv.y, a1);
                a2 = fmaf(qv[i].z, tv.z, a2);
                a3 = fmaf(qv[i].w, tv.w, a3);
            }
            float dot = (a0 + a1) + (a2 + a3);
            float d2 = x2l + sT2[p] - 2.f * dot;
            int gidx = (c * S_PER + t0 + p) * S_STRIDE;
            if (better(d2, gidx, bd[KNN - 1], bi[KNN - 1])) {
                bd[KNN - 1] = d2; bi[KNN - 1] = gidx;
                #pragma unroll
                for (int j = KNN - 1; j >= 1; --j) {
                    if (better(bd[j], bi[j], bd[j - 1], bi[j - 1])) {
                        float td = bd[j]; bd[j] = bd[j - 1]; bd[j - 1] = td;
                        int   ti = bi[j]; bi[j] = bi[j - 1]; bi[j - 1] = ti;
                    }
                }
            }
        }
    }

    float* cd = cand_d + ((size_t)q * S_CHUNKS + c) * KNN;
    int*   ci = cand_i + ((size_t)q * S_CHUNKS + c) * KNN;
    #pragma unroll
    for (int j = 0; j < KNN; ++j) { cd[j] = bd[j]; ci[j] = bi[j]; }
}

// ---------------------------------------------------------------------------
// Kernel 2: merge subsample candidates -> tau[q] = 16th-best d2.
__global__ void knn_tau(const float* __restrict__ cand_d,
                        const int* __restrict__ cand_i,
                        float* __restrict__ tau) {
    __shared__ float sd[S_CHUNKS * KNN];
    __shared__ int   si[S_CHUNKS * KNN];
    int q = blockIdx.x;
    int lane = threadIdx.x;
    const int nc = S_CHUNKS * KNN;
    const float* cd = cand_d + (size_t)q * nc;
    const int*   ci = cand_i + (size_t)q * nc;
    for (int i = lane; i < nc; i += 64) { sd[i] = cd[i]; si[i] = ci[i]; }
    __syncthreads();
    float last = 3.4e38f;
    #pragma unroll
    for (int sel = 0; sel < KNN; ++sel) {
        float md = 3.4e38f; int mi = 0x7fffffff; int ml = -1;
        for (int i = lane; i < nc; i += 64)
            if (better(sd[i], si[i], md, mi)) { md = sd[i]; mi = si[i]; ml = i; }
        #pragma unroll
        for (int off = 32; off > 0; off >>= 1) {
            float od = __shfl_down(md, off, 64);
            int   oi = __shfl_down(mi, off, 64);
            int   ol = __shfl_down(ml, off, 64);
            if (better(od, oi, md, mi)) { md = od; mi = oi; ml = ol; }
        }
        md = __shfl(md, 0, 64); ml = __shfl(ml, 0, 64);
        last = md;
        if (lane == 0 && ml >= 0) { sd[ml] = 3.4e38f; si[ml] = 0x7fffffff; }
        __syncthreads();
    }
    if (lane == 0) tau[q] = last;
}

// ---------------------------------------------------------------------------
// Kernel 3: bf16 MFMA filter. Block: 256 thr (4 waves), 128 queries x 3125
// train pts. A-frags (queries) cached in registers across all train tiles.
// Pass condition folded to: s >= 0.5*(x2[q]-tau[q]-MARGIN) + 0.5*t2[n].
__global__ __launch_bounds__(256, 2)
void knn_mfma_filter(const float* __restrict__ x, const float* __restrict__ train,
                     const float* __restrict__ t2, const float* __restrict__ x2,
                     const float* __restrict__ tau,
                     int* __restrict__ buf_i, int* __restrict__ cnt) {
    __shared__ short Q[MQ * QSTR];     // 34.8 KB
    __shared__ short T[TT * QSTR];     // 17.4 KB
    __shared__ float t2h[TT];

    int tid = threadIdx.x;
    int w = tid >> 6, lane = tid & 63;
    int rquad = lane >> 4, rcol = lane & 15;
    int qBase = blockIdx.y * MQ;
    int pBase = blockIdx.x * TC;

    // Stage queries -> bf16 LDS (RNE). 4096 float4s.
    #pragma unroll
    for (int it = 0; it < 16; ++it) {
        int f = it * 256 + tid;
        int row = f >> 5, c4 = f & 31;
        float4 v = ((const float4*)x)[(size_t)(qBase + row) * (DIM / 4) + c4];
        uint2 p; p.x = pack_bf16(v.x, v.y); p.y = pack_bf16(v.z, v.w);
        *(uint2*)&Q[row * QSTR + c4 * 4] = p;
    }
    __syncthreads();

    // Per-lane C-row constants (rows fixed for whole kernel).
    float RC[2][4];
    #pragma unroll
    for (int rt = 0; rt < 2; ++rt)
        #pragma unroll
        for (int reg = 0; reg < 4; ++reg) {
            int q = qBase + w * 32 + rt * 16 + rquad * 4 + reg;
            RC[rt][reg] = 0.5f * (x2[q] - tau[q] - MARGIN);
        }
    // A-fragment register cache: A[m=lane&15][k=(lane>>4)*8+j].
    bfrag A[2][4];
    #pragma unroll
    for (int rt = 0; rt < 2; ++rt)
        #pragma unroll
        for (int ks = 0; ks < 4; ++ks) {
            int r = w * 32 + rt * 16 + rcol;
            A[rt][ks] = *(const bfrag*)&Q[r * QSTR + ks * 32 + rquad * 8];
        }

    const cfrag zero4 = {0.f, 0.f, 0.f, 0.f};
    for (int t = 0; t < NT; ++t) {
        __syncthreads();
        int tBase = pBase + t * TT;
        // Stage train tile -> bf16 LDS. 2048 float4s, guarded for last tile.
        #pragma unroll
        for (int it = 0; it < 8; ++it) {
            int f = it * 256 + tid;
            int row = f >> 5, c4 = f & 31;
            bool ok = (t * TT + row) < TC;
            float4 v = ok ? ((const float4*)train)[(size_t)(tBase + row) * (DIM / 4) + c4]
                          : make_float4(0.f, 0.f, 0.f, 0.f);
            uint2 p; p.x = pack_bf16(v.x, v.y); p.y = pack_bf16(v.z, v.w);
            *(uint2*)&T[row * QSTR + c4 * 4] = p;
        }
        if (tid < TT)
            t2h[tid] = (t * TT + tid) < TC ? 0.5f * t2[tBase + tid] : 1e30f;
        __syncthreads();

        cfrag acc[2][4];
        #pragma unroll
        for (int ks = 0; ks < 4; ++ks) {
            bfrag B[4];
            #pragma unroll
            for (int ct = 0; ct < 4; ++ct) {
                int n = ct * 16 + rcol;
                B[ct] = *(const bfrag*)&T[n * QSTR + ks * 32 + rquad * 8];
            }
            #pragma unroll
            for (int rt = 0; rt < 2; ++rt)
                #pragma unroll
                for (int ct = 0; ct < 4; ++ct)
                    acc[rt][ct] = (ks == 0)
                        ? __builtin_amdgcn_mfma_f32_16x16x32_bf16(A[rt][0], B[ct], zero4, 0, 0, 0)
                        : __builtin_amdgcn_mfma_f32_16x16x32_bf16(A[rt][ks], B[ct], acc[rt][ct], 0, 0, 0);
        }

        float th[4];
        #pragma unroll
        for (int ct = 0; ct < 4; ++ct) th[ct] = t2h[ct * 16 + rcol];
        #pragma unroll
        for (int rt = 0; rt < 2; ++rt)
            #pragma unroll
            for (int ct = 0; ct < 4; ++ct)
                #pragma unroll
                for (int reg = 0; reg < 4; ++reg) {
                    float s = acc[rt][ct][reg];
                    if (s >= RC[rt][reg] + th[ct]) {
                        int q = qBase + w * 32 + rt * 16 + rquad * 4 + reg;
                        int slot = atomicAdd(&cnt[q], 1);
                        if (slot < CAP)
                            buf_i[(size_t)q * CAP + slot] = tBase + ct * 16 + rcol;
                    }
                }
    }
}

// ---------------------------------------------------------------------------
// Kernel 4: exact fp32 re-rank of pushed candidate indices + weighted vote.
__global__ void knn_final(const float* __restrict__ x,
                          const float* __restrict__ train,
                          const float* __restrict__ t2v,
                          const int* __restrict__ buf_i,
                          const int* __restrict__ cnt,
                          const int* __restrict__ labels,
                          float* __restrict__ out) {
    __shared__ float sd[CAP];
    __shared__ int   si[CAP];
    __shared__ float spr[NCLS];
    int q = blockIdx.x;
    int lane = threadIdx.x;   // 64
    int n = cnt[q]; if (n > CAP) n = CAP;

    float xa = x[(size_t)q * DIM + lane];
    float xb = x[(size_t)q * DIM + 64 + lane];
    float x2l = xa * xa + xb * xb;
    #pragma unroll
    for (int off = 32; off > 0; off >>= 1) x2l += __shfl_down(x2l, off, 64);
    x2l = __shfl(x2l, 0, 64);

    for (int i = 0; i < n; ++i) {
        int idx = buf_i[(size_t)q * CAP + i];
        float ta = train[(size_t)idx * DIM + lane];
        float tb = train[(size_t)idx * DIM + 64 + lane];
        float p = xa * ta + xb * tb;
        #pragma unroll
        for (int off = 32; off > 0; off >>= 1) p += __shfl_down(p, off, 64);
        if (lane == 0) { sd[i] = x2l + t2v[idx] - 2.f * p; si[i] = idx; }
    }
    __syncthreads();

    float kd[KNN];
    int   ki[KNN];
    #pragma unroll
    for (int sel = 0; sel < KNN; ++sel) {
        float md = 3.4e38f; int mi = 0x7fffffff; int ml = -1;
        for (int i = lane; i < n; i += 64)
            if (better(sd[i], si[i], md, mi)) { md = sd[i]; mi = si[i]; ml = i; }
        #pragma unroll
        for (int off = 32; off > 0; off >>= 1) {
            float od = __shfl_down(md, off, 64);
            int   oi = __shfl_down(mi, off, 64);
            int   ol = __shfl_down(ml, off, 64);
            if (better(od, oi, md, mi)) { md = od; mi = oi; ml = ol; }
        }
        md = __shfl(md, 0, 64); mi = __shfl(mi, 0, 64); ml = __shfl(ml, 0, 64);
        kd[sel] = md; ki[sel] = mi;
        if (lane == 0 && ml >= 0) { sd[ml] = 3.4e38f; si[ml] = 0x7fffffff; }
        __syncthreads();
    }

    if (lane == 0) {
        bool anyzero = false;
        float dist[KNN];
        #pragma unroll
        for (int j = 0; j < KNN; ++j) {
            dist[j] = sqrtf(fmaxf(kd[j], 0.f));
            if (dist[j] == 0.f) anyzero = true;
        }
        #pragma unroll
        for (int c = 0; c < NCLS; ++c) spr[c] = 0.f;
        #pragma unroll
        for (int j = 0; j < KNN; ++j) {
            float w = anyzero ? (dist[j] == 0.f ? 1.f : 0.f) : 1.f / dist[j];
            spr[labels[ki[j]]] += w;
        }
        float s = 0.f;
        #pragma unroll
        for (int c = 0; c < NCLS; ++c) s += spr[c];
        if (s == 0.f) s = 1.f;
        float inv = 1.f / s;
        float best = -1.f; int bc = 0;
        #pragma unroll
        for (int c = 0; c < NCLS; ++c) {
            float pv = spr[c] * inv;
            out[NQ + (size_t)q * NCLS + c] = pv;
            if (pv > best) { best = pv; bc = c; }
        }
        out[q] = (float)bc;
    }
}

// ---------------------------------------------------------------------------
extern "C" void kernel_launch(void* const* d_in, const int* in_sizes, int n_in,
                              void* d_out, int out_size, void* d_ws, size_t ws_size,
                              hipStream_t stream) {
    const float* x      = (const float*)d_in[0];
    const float* train  = (const float*)d_in[1];
    const int*   labels = (const int*)d_in[2];
    float* out = (float*)d_out;

    // Workspace (~19.8 MB; round-1 evidence: ws_size >= 26.6 MB).
    float* t2  = (float*)d_ws;                                  // 100352
    float* x2  = t2 + 100352;                                   // 2048
    float* tau = x2 + NQ;                                       // 2048
    int*   cnt = (int*)(tau + NQ);                              // 2048
    float* scd = (float*)(cnt + NQ);                            // 2048*50*16
    int*   sci = (int*)(scd + (size_t)NQ * S_CHUNKS * KNN);
    int*   bi  = (int*)(sci + (size_t)NQ * S_CHUNKS * KNN);     // 2048*768

    int nrows = M_TRAIN + NQ;
    knn_norms<<<(nrows * 64 + 255) / 256, 256, 0, stream>>>(train, x, t2, x2);
    knn_zero_cnt<<<(NQ + 255) / 256, 256, 0, stream>>>(cnt);

    dim3 g1(S_CHUNKS, NQ / 256);
    knn_sub_scan<<<g1, 256, 0, stream>>>(x, train, t2, scd, sci);

    knn_tau<<<NQ, 64, 0, stream>>>(scd, sci, tau);

    dim3 g3(CHUNKS, NQ / MQ);
    knn_mfma_filter<<<g3, 256, 0, stream>>>(x, train, t2, x2, tau, bi, cnt);

    knn_final<<<NQ, 64, 0, stream>>>(x, train, t2, bi, cnt, labels, out);
}

// Round 4
// 565.705 us; speedup vs baseline: 15.8114x; 1.9601x over previous
//
#include <hip/hip_runtime.h>
#include <hip/hip_fp16.h>
#include <math.h>

#define M_TRAIN 100000
#define NQ 2048
#define DIM 128
#define KNN 16
#define NCLS 10

// Subsample for tau: every 16th train point; padded to 6272 = 49 * 128.
#define S_STRIDE 16
#define S_CNT (M_TRAIN / S_STRIDE)     // 6250
#define S_PAD 6272
#define SCH 49                         // sub chunks
#define SPC 128                        // pts per chunk = 2 tiles of 64

// MFMA filter pass
#define CAP 768
#define CHUNKS 32
#define TC (M_TRAIN / CHUNKS)          // 3125
#define TT 64
#define NT ((TC + TT - 1) / TT)        // 49
#define MQ 128
#define QSTR 136                       // LDS row stride in shorts (128 + 8 pad)
#define MARGIN 3.0f                    // 2*eps(bf16 dot, ~8.5 sigma) + fp16 quant

using bfrag = __attribute__((ext_vector_type(8))) short;
using cfrag = __attribute__((ext_vector_type(4))) float;

__device__ __forceinline__ bool better(float d1, int i1, float d2, int i2) {
    return (d1 < d2) || (d1 == d2 && i1 < i2);
}

__device__ __forceinline__ unsigned pack_bf16(float a, float b) {
    unsigned ua = __float_as_uint(a), ub = __float_as_uint(b);
    ua += 0x7fffu + ((ua >> 16) & 1u);   // RNE
    ub += 0x7fffu + ((ub >> 16) & 1u);
    return (ua >> 16) | (ub & 0xffff0000u);
}

// ---------------------------------------------------------------------------
// Kernel 0: squared norms, one wave per row.
__global__ void knn_norms(const float* __restrict__ train,
                          const float* __restrict__ x,
                          float* __restrict__ t2, float* __restrict__ x2) {
    int gw = (blockIdx.x * blockDim.x + threadIdx.x) >> 6;
    int lane = threadIdx.x & 63;
    if (gw >= M_TRAIN + NQ) return;
    const float* r = (gw < M_TRAIN) ? (train + (size_t)gw * DIM)
                                    : (x + (size_t)(gw - M_TRAIN) * DIM);
    float a = r[lane];
    float b = r[lane + 64];
    float s = a * a + b * b;
    #pragma unroll
    for (int off = 32; off > 0; off >>= 1)
        s += __shfl_down(s, off, 64);
    if (lane == 0) {
        if (gw < M_TRAIN) t2[gw] = s; else x2[gw - M_TRAIN] = s;
    }
}

__global__ void knn_zero_cnt(int* __restrict__ cnt) {
    int i = blockIdx.x * blockDim.x + threadIdx.x;
    if (i < NQ) cnt[i] = 0;
}

// ---------------------------------------------------------------------------
// Kernel 1: MFMA approx-d2 over the stride-16 subsample -> fp16 matrix.
__global__ __launch_bounds__(256, 2)
void knn_sub_mfma(const float* __restrict__ x, const float* __restrict__ train,
                  const float* __restrict__ t2, const float* __restrict__ x2,
                  __half* __restrict__ dsub) {
    __shared__ short Q[MQ * QSTR];
    __shared__ short T[TT * QSTR];
    __shared__ float t2h[TT];
    int tid = threadIdx.x;
    int w = tid >> 6, lane = tid & 63;
    int rquad = lane >> 4, rcol = lane & 15;
    int qBase = blockIdx.y * MQ;
    int cBase = blockIdx.x * SPC;

    #pragma unroll
    for (int it = 0; it < 16; ++it) {
        int f = it * 256 + tid;
        int row = f >> 5, c4 = f & 31;
        float4 v = ((const float4*)x)[(size_t)(qBase + row) * (DIM / 4) + c4];
        uint2 p; p.x = pack_bf16(v.x, v.y); p.y = pack_bf16(v.z, v.w);
        *(uint2*)&Q[row * QSTR + c4 * 4] = p;
    }
    __syncthreads();

    float x2r[2][4];
    #pragma unroll
    for (int rt = 0; rt < 2; ++rt)
        #pragma unroll
        for (int reg = 0; reg < 4; ++reg)
            x2r[rt][reg] = x2[qBase + w * 32 + rt * 16 + rquad * 4 + reg];

    bfrag A[2][4];
    #pragma unroll
    for (int rt = 0; rt < 2; ++rt)
        #pragma unroll
        for (int ks = 0; ks < 4; ++ks) {
            int r = w * 32 + rt * 16 + rcol;
            A[rt][ks] = *(const bfrag*)&Q[r * QSTR + ks * 32 + rquad * 8];
        }

    const cfrag zero4 = {0.f, 0.f, 0.f, 0.f};
    for (int t = 0; t < 2; ++t) {
        __syncthreads();
        int sBase = cBase + t * TT;   // subsample index of tile row 0
        #pragma unroll
        for (int it = 0; it < 8; ++it) {
            int f = it * 256 + tid;
            int row = f >> 5, c4 = f & 31;
            int sj = sBase + row;
            bool ok = sj < S_CNT;
            float4 v = ok ? ((const float4*)train)[(size_t)sj * S_STRIDE * (DIM / 4) + c4]
                          : make_float4(0.f, 0.f, 0.f, 0.f);
            uint2 p; p.x = pack_bf16(v.x, v.y); p.y = pack_bf16(v.z, v.w);
            *(uint2*)&T[row * QSTR + c4 * 4] = p;
        }
        if (tid < TT) {
            int sj = sBase + tid;
            t2h[tid] = (sj < S_CNT) ? t2[(size_t)sj * S_STRIDE] : 1e30f;
        }
        __syncthreads();

        cfrag acc[2][4];
        #pragma unroll
        for (int ks = 0; ks < 4; ++ks) {
            bfrag B[4];
            #pragma unroll
            for (int ct = 0; ct < 4; ++ct) {
                int n = ct * 16 + rcol;
                B[ct] = *(const bfrag*)&T[n * QSTR + ks * 32 + rquad * 8];
            }
            #pragma unroll
            for (int rt = 0; rt < 2; ++rt)
                #pragma unroll
                for (int ct = 0; ct < 4; ++ct)
                    acc[rt][ct] = (ks == 0)
                        ? __builtin_amdgcn_mfma_f32_16x16x32_bf16(A[rt][0], B[ct], zero4, 0, 0, 0)
                        : __builtin_amdgcn_mfma_f32_16x16x32_bf16(A[rt][ks], B[ct], acc[rt][ct], 0, 0, 0);
        }

        float th[4];
        #pragma unroll
        for (int ct = 0; ct < 4; ++ct) th[ct] = t2h[ct * 16 + rcol];
        #pragma unroll
        for (int rt = 0; rt < 2; ++rt)
            #pragma unroll
            for (int ct = 0; ct < 4; ++ct)
                #pragma unroll
                for (int reg = 0; reg < 4; ++reg) {
                    float d2 = x2r[rt][reg] + th[ct] - 2.f * acc[rt][ct][reg];
                    int qrow = qBase + w * 32 + rt * 16 + rquad * 4 + reg;
                    int col = sBase + ct * 16 + rcol;
                    dsub[(size_t)qrow * S_PAD + col] = __float2half_rn(d2);
                }
    }
}

// ---------------------------------------------------------------------------
// Kernel 2: tau[q] = 16th-smallest value of dsub row q (values only).
__global__ __launch_bounds__(256)
void knn_select(const __half* __restrict__ dsub, float* __restrict__ tau) {
    __shared__ float wv[4];
    __shared__ int   wc[4];
    __shared__ float sv;
    __shared__ int   sc;
    int q = blockIdx.x, tid = threadIdx.x;
    int w = tid >> 6, lane = tid & 63;

    float bd[KNN];
    #pragma unroll
    for (int j = 0; j < KNN; ++j) bd[j] = 3.4e38f;
    for (int k = 0; k < 25; ++k) {
        int idx = k * 256 + tid;
        if (idx < S_PAD) {
            float v = __half2float(dsub[(size_t)q * S_PAD + idx]);
            if (v < bd[KNN - 1]) {
                bd[KNN - 1] = v;
                #pragma unroll
                for (int j = KNN - 1; j >= 1; --j)
                    if (bd[j] < bd[j - 1]) { float t = bd[j]; bd[j] = bd[j - 1]; bd[j - 1] = t; }
            }
        }
    }

    float last = 3.4e38f;
    for (int sel = 0; sel < KNN; ++sel) {
        float mv = bd[0]; int mj = 0;
        #pragma unroll
        for (int j = 1; j < KNN; ++j) if (bd[j] < mv) { mv = bd[j]; mj = j; }
        int mc = (tid << 4) | mj;
        #pragma unroll
        for (int off = 32; off > 0; off >>= 1) {
            float ov = __shfl_down(mv, off, 64);
            int   oc = __shfl_down(mc, off, 64);
            if (ov < mv) { mv = ov; mc = oc; }
        }
        if (lane == 0) { wv[w] = mv; wc[w] = mc; }
        __syncthreads();
        if (tid == 0) {
            float bv = wv[0]; int bc = wc[0];
            #pragma unroll
            for (int i = 1; i < 4; ++i) if (wv[i] < bv) { bv = wv[i]; bc = wc[i]; }
            sv = bv; sc = bc;
        }
        __syncthreads();
        last = sv;
        if (tid == (sc >> 4)) {
            int j0 = sc & 15;
            #pragma unroll
            for (int j = 0; j < KNN; ++j) if (j == j0) bd[j] = 3.4e38f;
        }
        __syncthreads();
    }
    if (tid == 0) tau[q] = last;
}

// ---------------------------------------------------------------------------
// Kernel 3: bf16 MFMA filter (unchanged structure; MARGIN widened for approx tau).
__global__ __launch_bounds__(256, 2)
void knn_mfma_filter(const float* __restrict__ x, const float* __restrict__ train,
                     const float* __restrict__ t2, const float* __restrict__ x2,
                     const float* __restrict__ tau,
                     int* __restrict__ buf_i, int* __restrict__ cnt) {
    __shared__ short Q[MQ * QSTR];
    __shared__ short T[TT * QSTR];
    __shared__ float t2h[TT];

    int tid = threadIdx.x;
    int w = tid >> 6, lane = tid & 63;
    int rquad = lane >> 4, rcol = lane & 15;
    int qBase = blockIdx.y * MQ;
    int pBase = blockIdx.x * TC;

    #pragma unroll
    for (int it = 0; it < 16; ++it) {
        int f = it * 256 + tid;
        int row = f >> 5, c4 = f & 31;
        float4 v = ((const float4*)x)[(size_t)(qBase + row) * (DIM / 4) + c4];
        uint2 p; p.x = pack_bf16(v.x, v.y); p.y = pack_bf16(v.z, v.w);
        *(uint2*)&Q[row * QSTR + c4 * 4] = p;
    }
    __syncthreads();

    float RC[2][4];
    #pragma unroll
    for (int rt = 0; rt < 2; ++rt)
        #pragma unroll
        for (int reg = 0; reg < 4; ++reg) {
            int q = qBase + w * 32 + rt * 16 + rquad * 4 + reg;
            RC[rt][reg] = 0.5f * (x2[q] - tau[q] - MARGIN);
        }
    bfrag A[2][4];
    #pragma unroll
    for (int rt = 0; rt < 2; ++rt)
        #pragma unroll
        for (int ks = 0; ks < 4; ++ks) {
            int r = w * 32 + rt * 16 + rcol;
            A[rt][ks] = *(const bfrag*)&Q[r * QSTR + ks * 32 + rquad * 8];
        }

    const cfrag zero4 = {0.f, 0.f, 0.f, 0.f};
    for (int t = 0; t < NT; ++t) {
        __syncthreads();
        int tBase = pBase + t * TT;
        #pragma unroll
        for (int it = 0; it < 8; ++it) {
            int f = it * 256 + tid;
            int row = f >> 5, c4 = f & 31;
            bool ok = (t * TT + row) < TC;
            float4 v = ok ? ((const float4*)train)[(size_t)(tBase + row) * (DIM / 4) + c4]
                          : make_float4(0.f, 0.f, 0.f, 0.f);
            uint2 p; p.x = pack_bf16(v.x, v.y); p.y = pack_bf16(v.z, v.w);
            *(uint2*)&T[row * QSTR + c4 * 4] = p;
        }
        if (tid < TT)
            t2h[tid] = (t * TT + tid) < TC ? 0.5f * t2[tBase + tid] : 1e30f;
        __syncthreads();

        cfrag acc[2][4];
        #pragma unroll
        for (int ks = 0; ks < 4; ++ks) {
            bfrag B[4];
            #pragma unroll
            for (int ct = 0; ct < 4; ++ct) {
                int n = ct * 16 + rcol;
                B[ct] = *(const bfrag*)&T[n * QSTR + ks * 32 + rquad * 8];
            }
            #pragma unroll
            for (int rt = 0; rt < 2; ++rt)
                #pragma unroll
                for (int ct = 0; ct < 4; ++ct)
                    acc[rt][ct] = (ks == 0)
                        ? __builtin_amdgcn_mfma_f32_16x16x32_bf16(A[rt][0], B[ct], zero4, 0, 0, 0)
                        : __builtin_amdgcn_mfma_f32_16x16x32_bf16(A[rt][ks], B[ct], acc[rt][ct], 0, 0, 0);
        }

        float th[4];
        #pragma unroll
        for (int ct = 0; ct < 4; ++ct) th[ct] = t2h[ct * 16 + rcol];
        #pragma unroll
        for (int rt = 0; rt < 2; ++rt)
            #pragma unroll
            for (int ct = 0; ct < 4; ++ct)
                #pragma unroll
                for (int reg = 0; reg < 4; ++reg) {
                    float s = acc[rt][ct][reg];
                    if (s >= RC[rt][reg] + th[ct]) {
                        int q = qBase + w * 32 + rt * 16 + rquad * 4 + reg;
                        int slot = atomicAdd(&cnt[q], 1);
                        if (slot < CAP)
                            buf_i[(size_t)q * CAP + slot] = tBase + ct * 16 + rcol;
                    }
                }
    }
}

// ---------------------------------------------------------------------------
// Kernel 4: exact fp32 re-rank + weighted vote. 256 thr: 16 lanes/candidate.
__global__ __launch_bounds__(256)
void knn_final(const float* __restrict__ x,
               const float* __restrict__ train,
               const float* __restrict__ t2v,
               const float* __restrict__ x2v,
               const int* __restrict__ buf_i,
               const int* __restrict__ cnt,
               const int* __restrict__ labels,
               float* __restrict__ out) {
    __shared__ float sd[CAP];
    __shared__ int   si[CAP];
    __shared__ float spr[NCLS];
    int q = blockIdx.x;
    int tid = threadIdx.x;
    int w = tid >> 6, lane = tid & 63;
    int grp = lane >> 4;     // candidate slot within wave
    int sub = lane & 15;     // 8-dim group
    int n = cnt[q]; if (n > CAP) n = CAP;

    const float4* xq = (const float4*)&x[(size_t)q * DIM + sub * 8];
    float4 qa = xq[0], qb = xq[1];
    float x2l = x2v[q];

    for (int base = 0; base < n; base += 16) {
        int i = base + w * 4 + grp;
        if (i < n) {
            int idx = buf_i[(size_t)q * CAP + i];
            const float4* tr = (const float4*)&train[(size_t)idx * DIM + sub * 8];
            float4 ta = tr[0], tb = tr[1];
            float s = qa.x * ta.x + qa.y * ta.y + qa.z * ta.z + qa.w * ta.w
                    + qb.x * tb.x + qb.y * tb.y + qb.z * tb.z + qb.w * tb.w;
            s += __shfl_xor(s, 1, 64);
            s += __shfl_xor(s, 2, 64);
            s += __shfl_xor(s, 4, 64);
            s += __shfl_xor(s, 8, 64);
            if (sub == 0) { sd[i] = x2l + t2v[idx] - 2.f * s; si[i] = idx; }
        }
    }
    __syncthreads();

    float kd[KNN];
    int   ki[KNN];
    for (int sel = 0; sel < KNN; ++sel) {
        if (w == 0) {
            float md = 3.4e38f; int mi = 0x7fffffff; int ml = -1;
            for (int i = lane; i < n; i += 64)
                if (better(sd[i], si[i], md, mi)) { md = sd[i]; mi = si[i]; ml = i; }
            #pragma unroll
            for (int off = 32; off > 0; off >>= 1) {
                float od = __shfl_down(md, off, 64);
                int   oi = __shfl_down(mi, off, 64);
                int   ol = __shfl_down(ml, off, 64);
                if (better(od, oi, md, mi)) { md = od; mi = oi; ml = ol; }
            }
            md = __shfl(md, 0, 64); mi = __shfl(mi, 0, 64); ml = __shfl(ml, 0, 64);
            kd[sel] = md; ki[sel] = mi;
            if (lane == 0 && ml >= 0) { sd[ml] = 3.4e38f; si[ml] = 0x7fffffff; }
        }
        __syncthreads();
    }

    if (tid == 0) {
        bool anyzero = false;
        float dist[KNN];
        #pragma unroll
        for (int j = 0; j < KNN; ++j) {
            dist[j] = sqrtf(fmaxf(kd[j], 0.f));
            if (dist[j] == 0.f) anyzero = true;
        }
        #pragma unroll
        for (int c = 0; c < NCLS; ++c) spr[c] = 0.f;
        #pragma unroll
        for (int j = 0; j < KNN; ++j) {
            float wgt = anyzero ? (dist[j] == 0.f ? 1.f : 0.f) : 1.f / dist[j];
            spr[labels[ki[j]]] += wgt;
        }
        float s = 0.f;
        #pragma unroll
        for (int c = 0; c < NCLS; ++c) s += spr[c];
        if (s == 0.f) s = 1.f;
        float inv = 1.f / s;
        float best = -1.f; int bc = 0;
        #pragma unroll
        for (int c = 0; c < NCLS; ++c) {
            float pv = spr[c] * inv;
            out[NQ + (size_t)q * NCLS + c] = pv;
            if (pv > best) { best = pv; bc = c; }
        }
        out[q] = (float)bc;
    }
}

// ---------------------------------------------------------------------------
extern "C" void kernel_launch(void* const* d_in, const int* in_sizes, int n_in,
                              void* d_out, int out_size, void* d_ws, size_t ws_size,
                              hipStream_t stream) {
    const float* x      = (const float*)d_in[0];
    const float* train  = (const float*)d_in[1];
    const int*   labels = (const int*)d_in[2];
    float* out = (float*)d_out;

    // ws: t2 | x2 | tau | cnt | dsub (aliased by buf_i after knn_select).
    // Total 24.9 MiB <= 25.4 MiB proven available in round 1.
    float*  t2   = (float*)d_ws;                 // 100352
    float*  x2   = t2 + 100352;                  // 2048
    float*  tau  = x2 + NQ;                      // 2048
    int*    cnt  = (int*)(tau + NQ);             // 2048
    __half* dsub = (__half*)(cnt + NQ);          // 2048*6272 fp16 = 24.5 MiB
    int*    bi   = (int*)dsub;                   // 2048*768 int (dead dsub)

    int nrows = M_TRAIN + NQ;
    knn_norms<<<(nrows * 64 + 255) / 256, 256, 0, stream>>>(train, x, t2, x2);
    knn_zero_cnt<<<(NQ + 255) / 256, 256, 0, stream>>>(cnt);

    dim3 gs(SCH, NQ / MQ);
    knn_sub_mfma<<<gs, 256, 0, stream>>>(x, train, t2, x2, dsub);

    knn_select<<<NQ, 256, 0, stream>>>(dsub, tau);

    dim3 g3(CHUNKS, NQ / MQ);
    knn_mfma_filter<<<g3, 256, 0, stream>>>(x, train, t2, x2, tau, bi, cnt);

    knn_final<<<NQ, 256, 0, stream>>>(x, train, t2, x2, bi, cnt, labels, out);
}

// Round 5
// 532.792 us; speedup vs baseline: 16.7881x; 1.0618x over previous
//
#include <hip/hip_runtime.h>
#include <hip/hip_fp16.h>
#include <math.h>

#define M_TRAIN 100000
#define NQ 2048
#define DIM 128
#define KNN 16
#define NCLS 10

// Subsample for tau: every 16th train point; padded to 6272 = 49 * 128.
#define S_STRIDE 16
#define S_CNT (M_TRAIN / S_STRIDE)     // 6250
#define S_PAD 6272
#define SCH 49
#define SPC 128

// MFMA filter pass
#define CAP 768
#define FCH 64                         // chunks (last one fully OOB-guarded)
#define FTC 1600                       // train pts per chunk
#define FNT 25                         // tiles per chunk (FTC/TT)
#define TT 64
#define MQ 128
#define QSTR 136                       // LDS row stride in shorts (128 + 8 pad)
#define MARGIN 3.0f

using bfrag = __attribute__((ext_vector_type(8))) short;
using cfrag = __attribute__((ext_vector_type(4))) float;

__device__ __forceinline__ bool better(float d1, int i1, float d2, int i2) {
    return (d1 < d2) || (d1 == d2 && i1 < i2);
}

__device__ __forceinline__ unsigned pack_bf16(float a, float b) {
    unsigned ua = __float_as_uint(a), ub = __float_as_uint(b);
    ua += 0x7fffu + ((ua >> 16) & 1u);   // RNE
    ub += 0x7fffu + ((ub >> 16) & 1u);
    return (ua >> 16) | (ub & 0xffff0000u);
}

// ---------------------------------------------------------------------------
// Kernel 0: squared norms, one wave per row.
__global__ void knn_norms(const float* __restrict__ train,
                          const float* __restrict__ x,
                          float* __restrict__ t2, float* __restrict__ x2) {
    int gw = (blockIdx.x * blockDim.x + threadIdx.x) >> 6;
    int lane = threadIdx.x & 63;
    if (gw >= M_TRAIN + NQ) return;
    const float* r = (gw < M_TRAIN) ? (train + (size_t)gw * DIM)
                                    : (x + (size_t)(gw - M_TRAIN) * DIM);
    float a = r[lane];
    float b = r[lane + 64];
    float s = a * a + b * b;
    #pragma unroll
    for (int off = 32; off > 0; off >>= 1)
        s += __shfl_down(s, off, 64);
    if (lane == 0) {
        if (gw < M_TRAIN) t2[gw] = s; else x2[gw - M_TRAIN] = s;
    }
}

__global__ void knn_zero_cnt(int* __restrict__ cnt) {
    int i = blockIdx.x * blockDim.x + threadIdx.x;
    if (i < NQ) cnt[i] = 0;
}

// ---------------------------------------------------------------------------
// Kernel 1: MFMA approx-d2 over the stride-16 subsample -> fp16 matrix.
__global__ __launch_bounds__(256, 2)
void knn_sub_mfma(const float* __restrict__ x, const float* __restrict__ train,
                  const float* __restrict__ t2, const float* __restrict__ x2,
                  __half* __restrict__ dsub) {
    __shared__ short Q[MQ * QSTR];
    __shared__ short T[TT * QSTR];
    __shared__ float t2h[TT];
    int tid = threadIdx.x;
    int w = tid >> 6, lane = tid & 63;
    int rquad = lane >> 4, rcol = lane & 15;
    int qBase = blockIdx.y * MQ;
    int cBase = blockIdx.x * SPC;

    #pragma unroll
    for (int it = 0; it < 16; ++it) {
        int f = it * 256 + tid;
        int row = f >> 5, c4 = f & 31;
        float4 v = ((const float4*)x)[(size_t)(qBase + row) * (DIM / 4) + c4];
        uint2 p; p.x = pack_bf16(v.x, v.y); p.y = pack_bf16(v.z, v.w);
        *(uint2*)&Q[row * QSTR + c4 * 4] = p;
    }
    __syncthreads();

    float x2r[2][4];
    #pragma unroll
    for (int rt = 0; rt < 2; ++rt)
        #pragma unroll
        for (int reg = 0; reg < 4; ++reg)
            x2r[rt][reg] = x2[qBase + w * 32 + rt * 16 + rquad * 4 + reg];

    bfrag A[2][4];
    #pragma unroll
    for (int rt = 0; rt < 2; ++rt)
        #pragma unroll
        for (int ks = 0; ks < 4; ++ks) {
            int r = w * 32 + rt * 16 + rcol;
            A[rt][ks] = *(const bfrag*)&Q[r * QSTR + ks * 32 + rquad * 8];
        }

    const cfrag zero4 = {0.f, 0.f, 0.f, 0.f};
    for (int t = 0; t < 2; ++t) {
        __syncthreads();
        int sBase = cBase + t * TT;
        #pragma unroll
        for (int it = 0; it < 8; ++it) {
            int f = it * 256 + tid;
            int row = f >> 5, c4 = f & 31;
            int sj = sBase + row;
            bool ok = sj < S_CNT;
            float4 v = ok ? ((const float4*)train)[(size_t)sj * S_STRIDE * (DIM / 4) + c4]
                          : make_float4(0.f, 0.f, 0.f, 0.f);
            uint2 p; p.x = pack_bf16(v.x, v.y); p.y = pack_bf16(v.z, v.w);
            *(uint2*)&T[row * QSTR + c4 * 4] = p;
        }
        if (tid < TT) {
            int sj = sBase + tid;
            t2h[tid] = (sj < S_CNT) ? t2[(size_t)sj * S_STRIDE] : 1e30f;
        }
        __syncthreads();

        cfrag acc[2][4];
        #pragma unroll
        for (int ks = 0; ks < 4; ++ks) {
            bfrag B[4];
            #pragma unroll
            for (int ct = 0; ct < 4; ++ct) {
                int n = ct * 16 + rcol;
                B[ct] = *(const bfrag*)&T[n * QSTR + ks * 32 + rquad * 8];
            }
            #pragma unroll
            for (int rt = 0; rt < 2; ++rt)
                #pragma unroll
                for (int ct = 0; ct < 4; ++ct)
                    acc[rt][ct] = (ks == 0)
                        ? __builtin_amdgcn_mfma_f32_16x16x32_bf16(A[rt][0], B[ct], zero4, 0, 0, 0)
                        : __builtin_amdgcn_mfma_f32_16x16x32_bf16(A[rt][ks], B[ct], acc[rt][ct], 0, 0, 0);
        }

        float th[4];
        #pragma unroll
        for (int ct = 0; ct < 4; ++ct) th[ct] = t2h[ct * 16 + rcol];
        #pragma unroll
        for (int rt = 0; rt < 2; ++rt)
            #pragma unroll
            for (int ct = 0; ct < 4; ++ct)
                #pragma unroll
                for (int reg = 0; reg < 4; ++reg) {
                    float d2 = x2r[rt][reg] + th[ct] - 2.f * acc[rt][ct][reg];
                    int qrow = qBase + w * 32 + rt * 16 + rquad * 4 + reg;
                    int col = sBase + ct * 16 + rcol;
                    dsub[(size_t)qrow * S_PAD + col] = __float2half_rn(d2);
                }
    }
}

// ---------------------------------------------------------------------------
// Kernel 2: tau[q] = 16th-smallest value of dsub row q (values only).
__global__ __launch_bounds__(256)
void knn_select(const __half* __restrict__ dsub, float* __restrict__ tau) {
    __shared__ float wv[4];
    __shared__ int   wc[4];
    __shared__ float sv;
    __shared__ int   sc;
    int q = blockIdx.x, tid = threadIdx.x;
    int w = tid >> 6, lane = tid & 63;

    float bd[KNN];
    #pragma unroll
    for (int j = 0; j < KNN; ++j) bd[j] = 3.4e38f;
    for (int k = 0; k < 25; ++k) {
        int idx = k * 256 + tid;
        if (idx < S_PAD) {
            float v = __half2float(dsub[(size_t)q * S_PAD + idx]);
            if (v < bd[KNN - 1]) {
                bd[KNN - 1] = v;
                #pragma unroll
                for (int j = KNN - 1; j >= 1; --j)
                    if (bd[j] < bd[j - 1]) { float t = bd[j]; bd[j] = bd[j - 1]; bd[j - 1] = t; }
            }
        }
    }

    float last = 3.4e38f;
    for (int sel = 0; sel < KNN; ++sel) {
        float mv = bd[0]; int mj = 0;
        #pragma unroll
        for (int j = 1; j < KNN; ++j) if (bd[j] < mv) { mv = bd[j]; mj = j; }
        int mc = (tid << 4) | mj;
        #pragma unroll
        for (int off = 32; off > 0; off >>= 1) {
            float ov = __shfl_down(mv, off, 64);
            int   oc = __shfl_down(mc, off, 64);
            if (ov < mv) { mv = ov; mc = oc; }
        }
        if (lane == 0) { wv[w] = mv; wc[w] = mc; }
        __syncthreads();
        if (tid == 0) {
            float bv = wv[0]; int bc = wc[0];
            #pragma unroll
            for (int i = 1; i < 4; ++i) if (wv[i] < bv) { bv = wv[i]; bc = wc[i]; }
            sv = bv; sc = bc;
        }
        __syncthreads();
        last = sv;
        if (tid == (sc >> 4)) {
            int j0 = sc & 15;
            #pragma unroll
            for (int j = 0; j < KNN; ++j) if (j == j0) bd[j] = 3.4e38f;
        }
        __syncthreads();
    }
    if (tid == 0) tau[q] = last;
}

// ---------------------------------------------------------------------------
// Kernel 3: bf16 MFMA filter, software-pipelined.
// LDS: Q staging reuses the double-buffered T region (Q dead after A-frag init).
// One barrier per tile; loads for tile t+1 prefetched into regs before compute(t).
__global__ __launch_bounds__(256, 4)
void knn_mfma_filter(const float* __restrict__ x, const float* __restrict__ train,
                     const float* __restrict__ t2, const float* __restrict__ x2,
                     const float* __restrict__ tau,
                     int* __restrict__ buf_i, int* __restrict__ cnt) {
    __shared__ short SB[2][TT * QSTR];   // 34816 B total; also Q staging (17408 shorts)
    __shared__ float t2h[2][TT];

    int tid = threadIdx.x;
    int w = tid >> 6, lane = tid & 63;
    int rquad = lane >> 4, rcol = lane & 15;

    // XCD swizzle: all 16 q-blocks of a chunk land on one XCD (L2 locality).
    int bid = blockIdx.x;
    int xcd = bid & 7, k = bid >> 3;
    int chunk = (k >> 4) * 8 + xcd;      // [0,64)
    int qb = k & 15;
    int qBase = qb * MQ;
    int pBase = chunk * FTC;

    // ---- Stage queries into SB-as-Q, build A-frags + RC, release SB.
    short* Q = &SB[0][0];
    #pragma unroll
    for (int it = 0; it < 16; ++it) {
        int f = it * 256 + tid;
        int row = f >> 5, c4 = f & 31;
        float4 v = ((const float4*)x)[(size_t)(qBase + row) * (DIM / 4) + c4];
        uint2 p; p.x = pack_bf16(v.x, v.y); p.y = pack_bf16(v.z, v.w);
        *(uint2*)&Q[row * QSTR + c4 * 4] = p;
    }
    __syncthreads();

    float RC[2][4];
    #pragma unroll
    for (int rt = 0; rt < 2; ++rt)
        #pragma unroll
        for (int reg = 0; reg < 4; ++reg) {
            int q = qBase + w * 32 + rt * 16 + rquad * 4 + reg;
            RC[rt][reg] = 0.5f * (x2[q] - tau[q] - MARGIN);
        }
    bfrag A[2][4];
    #pragma unroll
    for (int rt = 0; rt < 2; ++rt)
        #pragma unroll
        for (int ks = 0; ks < 4; ++ks) {
            int r = w * 32 + rt * 16 + rcol;
            A[rt][ks] = *(const bfrag*)&Q[r * QSTR + ks * 32 + rquad * 8];
        }
    __syncthreads();   // all waves done reading Q; SB free for tiles

    int srow = tid >> 5, sc4 = tid & 31;     // staging coords (row step 8/iter)
    float4 v[8];
    float tt;

    // Prologue: load tile 0 -> regs, pack -> SB[0].
    {
        int tBase = pBase;
        #pragma unroll
        for (int it = 0; it < 8; ++it) {
            int gr = tBase + it * 8 + srow;
            v[it] = (gr < M_TRAIN) ? ((const float4*)train)[(size_t)gr * (DIM / 4) + sc4]
                                   : make_float4(0.f, 0.f, 0.f, 0.f);
        }
        tt = 0.f;
        if (tid < TT) {
            int gr = tBase + tid;
            tt = (gr < M_TRAIN) ? 0.5f * t2[gr] : 1e30f;
        }
        #pragma unroll
        for (int it = 0; it < 8; ++it) {
            uint2 p; p.x = pack_bf16(v[it].x, v[it].y); p.y = pack_bf16(v[it].z, v[it].w);
            *(uint2*)&SB[0][(it * 8 + srow) * QSTR + sc4 * 4] = p;
        }
        if (tid < TT) t2h[0][tid] = tt;
    }
    __syncthreads();

    const cfrag zero4 = {0.f, 0.f, 0.f, 0.f};
    for (int t = 0; t < FNT; ++t) {
        int cur = t & 1, nxt = cur ^ 1;

        // Prefetch tile t+1 into regs (latency overlapped with compute below).
        if (t + 1 < FNT) {
            int tBase = pBase + (t + 1) * TT;
            #pragma unroll
            for (int it = 0; it < 8; ++it) {
                int gr = tBase + it * 8 + srow;
                v[it] = (gr < M_TRAIN) ? ((const float4*)train)[(size_t)gr * (DIM / 4) + sc4]
                                       : make_float4(0.f, 0.f, 0.f, 0.f);
            }
            tt = 0.f;
            if (tid < TT) {
                int gr = tBase + tid;
                tt = (gr < M_TRAIN) ? 0.5f * t2[gr] : 1e30f;
            }
        }

        // Compute on SB[cur].
        cfrag acc[2][4];
        #pragma unroll
        for (int ks = 0; ks < 4; ++ks) {
            bfrag B[4];
            #pragma unroll
            for (int ct = 0; ct < 4; ++ct) {
                int n = ct * 16 + rcol;
                B[ct] = *(const bfrag*)&SB[cur][n * QSTR + ks * 32 + rquad * 8];
            }
            #pragma unroll
            for (int rt = 0; rt < 2; ++rt)
                #pragma unroll
                for (int ct = 0; ct < 4; ++ct)
                    acc[rt][ct] = (ks == 0)
                        ? __builtin_amdgcn_mfma_f32_16x16x32_bf16(A[rt][0], B[ct], zero4, 0, 0, 0)
                        : __builtin_amdgcn_mfma_f32_16x16x32_bf16(A[rt][ks], B[ct], acc[rt][ct], 0, 0, 0);
        }

        float th[4];
        #pragma unroll
        for (int ct = 0; ct < 4; ++ct) th[ct] = t2h[cur][ct * 16 + rcol];
        int tBaseCur = pBase + t * TT;
        #pragma unroll
        for (int rt = 0; rt < 2; ++rt)
            #pragma unroll
            for (int ct = 0; ct < 4; ++ct)
                #pragma unroll
                for (int reg = 0; reg < 4; ++reg) {
                    float s = acc[rt][ct][reg];
                    if (s >= RC[rt][reg] + th[ct]) {
                        int q = qBase + w * 32 + rt * 16 + rquad * 4 + reg;
                        int slot = atomicAdd(&cnt[q], 1);
                        if (slot < CAP)
                            buf_i[(size_t)q * CAP + slot] = tBaseCur + ct * 16 + rcol;
                    }
                }

        // Pack prefetched tile into the other buffer (safe: compute(t-1) on it
        // finished before the barrier at end of iteration t-1).
        if (t + 1 < FNT) {
            #pragma unroll
            for (int it = 0; it < 8; ++it) {
                uint2 p; p.x = pack_bf16(v[it].x, v[it].y); p.y = pack_bf16(v[it].z, v[it].w);
                *(uint2*)&SB[nxt][(it * 8 + srow) * QSTR + sc4 * 4] = p;
            }
            if (tid < TT) t2h[nxt][tid] = tt;
        }
        __syncthreads();
    }
}

// ---------------------------------------------------------------------------
// Kernel 4: exact fp32 re-rank + weighted vote. 256 thr: 16 lanes/candidate.
__global__ __launch_bounds__(256)
void knn_final(const float* __restrict__ x,
               const float* __restrict__ train,
               const float* __restrict__ t2v,
               const float* __restrict__ x2v,
               const int* __restrict__ buf_i,
               const int* __restrict__ cnt,
               const int* __restrict__ labels,
               float* __restrict__ out) {
    __shared__ float sd[CAP];
    __shared__ int   si[CAP];
    __shared__ float spr[NCLS];
    int q = blockIdx.x;
    int tid = threadIdx.x;
    int w = tid >> 6, lane = tid & 63;
    int grp = lane >> 4;
    int sub = lane & 15;
    int n = cnt[q]; if (n > CAP) n = CAP;

    const float4* xq = (const float4*)&x[(size_t)q * DIM + sub * 8];
    float4 qa = xq[0], qb = xq[1];
    float x2l = x2v[q];

    for (int base = 0; base < n; base += 16) {
        int i = base + w * 4 + grp;
        if (i < n) {
            int idx = buf_i[(size_t)q * CAP + i];
            const float4* tr = (const float4*)&train[(size_t)idx * DIM + sub * 8];
            float4 ta = tr[0], tb = tr[1];
            float s = qa.x * ta.x + qa.y * ta.y + qa.z * ta.z + qa.w * ta.w
                    + qb.x * tb.x + qb.y * tb.y + qb.z * tb.z + qb.w * tb.w;
            s += __shfl_xor(s, 1, 64);
            s += __shfl_xor(s, 2, 64);
            s += __shfl_xor(s, 4, 64);
            s += __shfl_xor(s, 8, 64);
            if (sub == 0) { sd[i] = x2l + t2v[idx] - 2.f * s; si[i] = idx; }
        }
    }
    __syncthreads();

    float kd[KNN];
    int   ki[KNN];
    for (int sel = 0; sel < KNN; ++sel) {
        if (w == 0) {
            float md = 3.4e38f; int mi = 0x7fffffff; int ml = -1;
            for (int i = lane; i < n; i += 64)
                if (better(sd[i], si[i], md, mi)) { md = sd[i]; mi = si[i]; ml = i; }
            #pragma unroll
            for (int off = 32; off > 0; off >>= 1) {
                float od = __shfl_down(md, off, 64);
                int   oi = __shfl_down(mi, off, 64);
                int   ol = __shfl_down(ml, off, 64);
                if (better(od, oi, md, mi)) { md = od; mi = oi; ml = ol; }
            }
            md = __shfl(md, 0, 64); mi = __shfl(mi, 0, 64); ml = __shfl(ml, 0, 64);
            kd[sel] = md; ki[sel] = mi;
            if (lane == 0 && ml >= 0) { sd[ml] = 3.4e38f; si[ml] = 0x7fffffff; }
        }
        __syncthreads();
    }

    if (tid == 0) {
        bool anyzero = false;
        float dist[KNN];
        #pragma unroll
        for (int j = 0; j < KNN; ++j) {
            dist[j] = sqrtf(fmaxf(kd[j], 0.f));
            if (dist[j] == 0.f) anyzero = true;
        }
        #pragma unroll
        for (int c = 0; c < NCLS; ++c) spr[c] = 0.f;
        #pragma unroll
        for (int j = 0; j < KNN; ++j) {
            float wgt = anyzero ? (dist[j] == 0.f ? 1.f : 0.f) : 1.f / dist[j];
            spr[labels[ki[j]]] += wgt;
        }
        float s = 0.f;
        #pragma unroll
        for (int c = 0; c < NCLS; ++c) s += spr[c];
        if (s == 0.f) s = 1.f;
        float inv = 1.f / s;
        float best = -1.f; int bc = 0;
        #pragma unroll
        for (int c = 0; c < NCLS; ++c) {
            float pv = spr[c] * inv;
            out[NQ + (size_t)q * NCLS + c] = pv;
            if (pv > best) { best = pv; bc = c; }
        }
        out[q] = (float)bc;
    }
}

// ---------------------------------------------------------------------------
extern "C" void kernel_launch(void* const* d_in, const int* in_sizes, int n_in,
                              void* d_out, int out_size, void* d_ws, size_t ws_size,
                              hipStream_t stream) {
    const float* x      = (const float*)d_in[0];
    const float* train  = (const float*)d_in[1];
    const int*   labels = (const int*)d_in[2];
    float* out = (float*)d_out;

    // ws: t2 | x2 | tau | cnt | dsub (aliased by buf_i after knn_select).
    float*  t2   = (float*)d_ws;                 // 100352
    float*  x2   = t2 + 100352;                  // 2048
    float*  tau  = x2 + NQ;                      // 2048
    int*    cnt  = (int*)(tau + NQ);             // 2048
    __half* dsub = (__half*)(cnt + NQ);          // 2048*6272 fp16 = 24.5 MiB
    int*    bi   = (int*)dsub;                   // 2048*768 int (dead dsub)

    int nrows = M_TRAIN + NQ;
    knn_norms<<<(nrows * 64 + 255) / 256, 256, 0, stream>>>(train, x, t2, x2);
    knn_zero_cnt<<<(NQ + 255) / 256, 256, 0, stream>>>(cnt);

    dim3 gs(SCH, NQ / MQ);
    knn_sub_mfma<<<gs, 256, 0, stream>>>(x, train, t2, x2, dsub);

    knn_select<<<NQ, 256, 0, stream>>>(dsub, tau);

    knn_mfma_filter<<<FCH * (NQ / MQ), 256, 0, stream>>>(x, train, t2, x2, tau, bi, cnt);

    knn_final<<<NQ, 256, 0, stream>>>(x, train, t2, x2, bi, cnt, labels, out);
}